// Round 4
// baseline (162.788 us; speedup 1.0000x reference)
//
#include <hip/hip_runtime.h>
#include <hip/hip_cooperative_groups.h>

namespace cg = cooperative_groups;

#define EPS 1e-5f
#define NBLK 1024

// Math: theta_p = mean(x[b,0,6p:6p+6,0:6]); c_p = cos(theta_p);
// CNOT chain (0,1)(1,2)(2,3)(3,0) is a classical XOR map =>
// z0=c1*c2*c3, z1=c0*c1, z2=c0*c1*c2, z3=c0*c1*c2*c3; then batchnorm over B.
//
// Needed float4 slots per image: j = 7r (cols 0-3) and 7r+1 (cols 4-5) for rows r=0..23.
// All needed bytes lie in [0, 2688) = float4 j in [0,168). We read that range densely
// (sequential request stream, full 128B lines) and mask unneeded elements in registers.
//
// ws layout: [0, 32768): float partials[NBLK][8] = {sum[4], sumsq[4]}

__global__ __launch_bounds__(256, 4) void qnat_fused(const float* __restrict__ x,
                                                     const float* __restrict__ gamma,
                                                     const float* __restrict__ beta,
                                                     float* __restrict__ out,
                                                     float* __restrict__ partials,
                                                     int bsz, int ipb) {
    __shared__ float zsh[64][4];   // per-block z values
    __shared__ float ps[4][8];     // per-wave {sum[4],sumsq[4]}
    __shared__ float red[4][8];    // phase-B per-wave stat partials
    __shared__ float st[8];        // {mean[4], scale[4]}

    const int t    = threadIdx.x;
    const int lane = t & 63;
    const int w    = t >> 6;
    const int ipw  = ipb >> 2;                 // images per wave
    const int blk0 = blockIdx.x * ipb;

    float s1[4] = {0.f,0.f,0.f,0.f};
    float s2[4] = {0.f,0.f,0.f,0.f};

    // ---- Phase A: theta -> c -> z, per-block stat partials ----
    for (int i = 0; i < ipw; ++i) {
        const int il  = w * ipw + i;
        const int img = blk0 + il;
        float a0 = 0.f, a1 = 0.f, a2 = 0.f, a3 = 0.f;
        if (img < bsz) {
            const float* ip = x + (size_t)img * 784;
            #pragma unroll
            for (int r = 0; r < 3; ++r) {
                const int j = r * 64 + lane;   // float4 index
                if (r < 2 || lane < 40) {      // j < 168
                    const float4 v = *reinterpret_cast<const float4*>(ip + 4 * j);
                    const int m = j % 7;       // col-phase: only 0,1 contribute
                    const int p = j / 42;      // theta index
                    float contrib = 0.f;
                    if (m == 0)      contrib = (v.x + v.y) + (v.z + v.w);  // cols 0-3
                    else if (m == 1) contrib = v.x + v.y;                  // cols 4-5
                    a0 += (p == 0) ? contrib : 0.f;
                    a1 += (p == 1) ? contrib : 0.f;
                    a2 += (p == 2) ? contrib : 0.f;
                    a3 += (p == 3) ? contrib : 0.f;
                }
            }
        }
        #pragma unroll
        for (int off = 1; off < 64; off <<= 1) {
            a0 += __shfl_xor(a0, off, 64);
            a1 += __shfl_xor(a1, off, 64);
            a2 += __shfl_xor(a2, off, 64);
            a3 += __shfl_xor(a3, off, 64);
        }
        const float k = 1.0f / 36.0f;
        const float c0 = __cosf(a0 * k), c1 = __cosf(a1 * k);
        const float c2 = __cosf(a2 * k), c3 = __cosf(a3 * k);
        const float z1 = c0 * c1;
        const float z2 = z1 * c2;
        const float z3 = z2 * c3;
        const float z0 = c1 * c2 * c3;
        if (img < bsz) {
            if (lane == 0) {
                float4 zz; zz.x = z0; zz.y = z1; zz.z = z2; zz.w = z3;
                *reinterpret_cast<float4*>(&zsh[il][0]) = zz;
            }
            s1[0] += z0; s1[1] += z1; s1[2] += z2; s1[3] += z3;
            s2[0] += z0*z0; s2[1] += z1*z1; s2[2] += z2*z2; s2[3] += z3*z3;
        }
    }
    if (lane == 0) {
        #pragma unroll
        for (int k = 0; k < 4; ++k) { ps[w][k] = s1[k]; ps[w][4+k] = s2[k]; }
    }
    __syncthreads();
    if (t < 8) {
        partials[blockIdx.x * 8 + t] = (ps[0][t] + ps[1][t]) + (ps[2][t] + ps[3][t]);
    }

    cg::this_grid().sync();

    // ---- Phase B: every block redundantly reduces the partials table ----
    {
        const int k  = t & 7;
        const int r0 = t >> 3;                 // 0..31
        float acc = 0.f;
        #pragma unroll 4
        for (int i = 0; i < NBLK / 32; ++i) {
            acc += partials[(r0 + 32 * i) * 8 + k];
        }
        acc += __shfl_xor(acc, 8, 64);
        acc += __shfl_xor(acc, 16, 64);
        acc += __shfl_xor(acc, 32, 64);
        if (lane < 8) red[w][lane] = acc;      // lane==k for lane<8
        __syncthreads();
        if (t < 8) st[t] = (red[0][t] + red[1][t]) + (red[2][t] + red[3][t]);
        __syncthreads();
        if (t < 4) {
            const double invB = 1.0 / (double)bsz;
            const double m   = (double)st[t] * invB;
            const double var = (double)st[4 + t] * invB - m * m;
            st[t]     = (float)m;
            st[4 + t] = gamma[t] * rsqrtf((float)var + EPS);
        }
        __syncthreads();
    }

    // ---- Phase C: normalize from LDS, write out ----
    if (t < 64 && t < ipb) {
        const int img = blk0 + t;
        if (img < bsz) {
            const float4 zv = *reinterpret_cast<const float4*>(&zsh[t][0]);
            float4 o;
            o.x = (zv.x - st[0]) * st[4] + beta[0];
            o.y = (zv.y - st[1]) * st[5] + beta[1];
            o.z = (zv.z - st[2]) * st[6] + beta[2];
            o.w = (zv.w - st[3]) * st[7] + beta[3];
            *reinterpret_cast<float4*>(out + (size_t)img * 4) = o;
        }
    }
}

extern "C" void kernel_launch(void* const* d_in, const int* in_sizes, int n_in,
                              void* d_out, int out_size, void* d_ws, size_t ws_size,
                              hipStream_t stream) {
    const float* x     = (const float*)d_in[0];
    const float* gamma = (const float*)d_in[1];
    const float* beta  = (const float*)d_in[2];
    float* out = (float*)d_out;

    const int bsz = in_sizes[0] / 784;
    float* partials = (float*)d_ws;

    int ipb = (bsz + NBLK - 1) / NBLK;
    ipb = (ipb + 3) & ~3;                      // multiple of 4 (one image set per wave)
    if (ipb > 64) ipb = 64;                    // LDS capacity guard (bsz <= 65536)

    void* args[] = { (void*)&x, (void*)&gamma, (void*)&beta, (void*)&out,
                     (void*)&partials, (void*)&bsz, (void*)&ipb };
    hipLaunchCooperativeKernel((const void*)qnat_fused, dim3(NBLK), dim3(256),
                               args, 0, stream);
}

// Round 5
// 41.998 us; speedup vs baseline: 3.8760x; 3.8760x over previous
//
#include <hip/hip_runtime.h>

#define EPS 1e-5f

// Math: theta_p = mean(x[b,0,6p:6p+6,0:6]); c_p = cos(theta_p);
// CNOT chain (0,1)(1,2)(2,3)(3,0) is a classical XOR map =>
// z0=c1*c2*c3, z1=c0*c1, z2=c0*c1*c2, z3=c0*c1*c2*c3; then batchnorm over B.
//
// Needed bytes per image all lie in [0, 2688) = float4 j in [0,168). Read densely
// (sequential request stream, full lines), mask unneeded elements in registers.
//
// ws layout:
//   [0, bsz*16)            float z[bsz][4]
//   [bsz*16, +NB*32)       float partials[NB][8] = {sum[4], sumsq[4]},  NB = ceil(bsz/16)

__global__ __launch_bounds__(256) void qnat_k1(const float* __restrict__ x,
                                               float* __restrict__ z_out,
                                               float* __restrict__ partials,
                                               int bsz) {
    const int t    = threadIdx.x;
    const int lane = t & 63;
    const int w    = t >> 6;           // wave 0..3
    const int imgBase = blockIdx.x * 16;

    float s1[4] = {0.f, 0.f, 0.f, 0.f};
    float s2[4] = {0.f, 0.f, 0.f, 0.f};

    #pragma unroll
    for (int iter = 0; iter < 4; ++iter) {
        const int img = imgBase + iter * 4 + w;   // one image per wave
        float a0 = 0.f, a1 = 0.f, a2 = 0.f, a3 = 0.f;
        if (img < bsz) {
            const float* ip = x + (size_t)img * 784;
            #pragma unroll
            for (int r = 0; r < 3; ++r) {
                const int j = r * 64 + lane;       // float4 index
                if (r < 2 || lane < 40) {          // j < 168: only needed lines
                    const float4 v = *reinterpret_cast<const float4*>(ip + 4 * j);
                    const int m = j % 7;           // col-phase: only 0,1 contribute
                    const int p = j / 42;          // theta index
                    float contrib = 0.f;
                    if (m == 0)      contrib = (v.x + v.y) + (v.z + v.w);  // cols 0-3
                    else if (m == 1) contrib = v.x + v.y;                  // cols 4-5
                    a0 += (p == 0) ? contrib : 0.f;
                    a1 += (p == 1) ? contrib : 0.f;
                    a2 += (p == 2) ? contrib : 0.f;
                    a3 += (p == 3) ? contrib : 0.f;
                }
            }
        }
        // full-wave butterfly: every lane ends with the four 36-elem sums
        #pragma unroll
        for (int off = 1; off < 64; off <<= 1) {
            a0 += __shfl_xor(a0, off, 64);
            a1 += __shfl_xor(a1, off, 64);
            a2 += __shfl_xor(a2, off, 64);
            a3 += __shfl_xor(a3, off, 64);
        }
        const float k = 1.0f / 36.0f;
        const float c0 = __cosf(a0 * k), c1 = __cosf(a1 * k);
        const float c2 = __cosf(a2 * k), c3 = __cosf(a3 * k);
        const float z1 = c0 * c1;
        const float z2 = z1 * c2;
        const float z3 = z2 * c3;
        const float z0 = c1 * c2 * c3;
        if (img < bsz) {
            if (lane == 0) {
                float4 zz; zz.x = z0; zz.y = z1; zz.z = z2; zz.w = z3;
                *reinterpret_cast<float4*>(z_out + (size_t)img * 4) = zz;
            }
            s1[0] += z0; s1[1] += z1; s1[2] += z2; s1[3] += z3;
            s2[0] += z0 * z0; s2[1] += z1 * z1; s2[2] += z2 * z2; s2[3] += z3 * z3;
        }
    }

    // combine 4 waves' (identical-per-lane) partials -> 8 floats per block
    __shared__ float ps[4][8];
    if (lane == 0) {
        #pragma unroll
        for (int k = 0; k < 4; ++k) { ps[w][k] = s1[k]; ps[w][4 + k] = s2[k]; }
    }
    __syncthreads();
    if (t < 8) {
        partials[blockIdx.x * 8 + t] = (ps[0][t] + ps[1][t]) + (ps[2][t] + ps[3][t]);
    }
}

// Every block redundantly reduces the partials table (L2-resident, ~128 KB),
// computes {mean, scale}, then normalizes its own 256 images. No serial phase.
__global__ __launch_bounds__(256) void qnat_k2(const float* __restrict__ z,
                                               const float* __restrict__ partials,
                                               const float* __restrict__ gamma,
                                               const float* __restrict__ beta,
                                               float* __restrict__ out,
                                               int NB, int bsz) {
    __shared__ float red[4][8];
    __shared__ float st[8];

    const int t = threadIdx.x, lane = t & 63, w = t >> 6;

    float acc[8] = {0.f,0.f,0.f,0.f,0.f,0.f,0.f,0.f};
    for (int r = t; r < NB; r += 256) {
        const float4 a = *reinterpret_cast<const float4*>(partials + r * 8);
        const float4 b = *reinterpret_cast<const float4*>(partials + r * 8 + 4);
        acc[0] += a.x; acc[1] += a.y; acc[2] += a.z; acc[3] += a.w;
        acc[4] += b.x; acc[5] += b.y; acc[6] += b.z; acc[7] += b.w;
    }
    #pragma unroll
    for (int off = 1; off < 64; off <<= 1) {
        #pragma unroll
        for (int k = 0; k < 8; ++k) acc[k] += __shfl_xor(acc[k], off, 64);
    }
    if (lane == 0) {
        #pragma unroll
        for (int k = 0; k < 8; ++k) red[w][k] = acc[k];
    }
    __syncthreads();
    if (t < 8) st[t] = (red[0][t] + red[1][t]) + (red[2][t] + red[3][t]);
    __syncthreads();
    if (t < 4) {
        const double invB = 1.0 / (double)bsz;
        const double m   = (double)st[t] * invB;
        const double var = (double)st[4 + t] * invB - m * m;
        st[t]     = (float)m;
        st[4 + t] = gamma[t] * rsqrtf((float)var + EPS);
    }
    __syncthreads();

    const int img = blockIdx.x * 256 + t;
    if (img < bsz) {
        const float4 zv = reinterpret_cast<const float4*>(z)[img];
        float4 o;
        o.x = (zv.x - st[0]) * st[4] + beta[0];
        o.y = (zv.y - st[1]) * st[5] + beta[1];
        o.z = (zv.z - st[2]) * st[6] + beta[2];
        o.w = (zv.w - st[3]) * st[7] + beta[3];
        reinterpret_cast<float4*>(out)[img] = o;
    }
}

extern "C" void kernel_launch(void* const* d_in, const int* in_sizes, int n_in,
                              void* d_out, int out_size, void* d_ws, size_t ws_size,
                              hipStream_t stream) {
    const float* x     = (const float*)d_in[0];
    const float* gamma = (const float*)d_in[1];
    const float* beta  = (const float*)d_in[2];
    float* out = (float*)d_out;

    const int bsz = in_sizes[0] / 784;
    const int NB  = (bsz + 15) / 16;

    float* z        = (float*)d_ws;
    float* partials = (float*)((char*)d_ws + (size_t)bsz * 16);

    qnat_k1<<<NB, 256, 0, stream>>>(x, z, partials, bsz);
    qnat_k2<<<(bsz + 255) / 256, 256, 0, stream>>>(z, partials, gamma, beta, out, NB, bsz);
}

// Round 6
// 39.871 us; speedup vs baseline: 4.0829x; 1.0534x over previous
//
#include <hip/hip_runtime.h>

#define EPS 1e-5f

// Math: theta_p = mean(x[b,0,6p:6p+6,0:6]); c_p = cos(theta_p);
// CNOT chain (0,1)(1,2)(2,3)(3,0) is a classical XOR map =>
// z0=c1*c2*c3, z1=c0*c1, z2=c0*c1*c2, z3=c0*c1*c2*c3; then batchnorm over B.
//
// Needed bytes per image all lie in [0, 2688) = float4 j in [0,168). Read densely
// (sequential request stream, full 128B lines), mask unneeded elements in registers.
//
// ws layout:
//   [0, bsz*16)            float z[bsz][4]
//   [bsz*16, +NB*32)       float partials[NB][8] = {sum[4], sumsq[4]},  NB = ceil(bsz/16)

__global__ __launch_bounds__(256) void qnat_k1(const float* __restrict__ x,
                                               float* __restrict__ z_out,
                                               float* __restrict__ partials,
                                               int bsz) {
    const int t    = threadIdx.x;
    const int lane = t & 63;
    const int w    = t >> 6;                  // wave 0..3
    const int img0 = blockIdx.x * 16 + w * 4; // this wave's 4 consecutive images

    // per-lane slot constants, identical for every image (j = r*64 + lane)
    const int j1 = 64 + lane, j2 = 128 + lane;
    const int m0 = lane % 7, p0 = lane / 42;
    const int m1 = j1 % 7,   p1 = j1 / 42;
    const int m2 = j2 % 7,   p2 = j2 / 42;

    float s1[4] = {0.f, 0.f, 0.f, 0.f};
    float s2[4] = {0.f, 0.f, 0.f, 0.f};

    #pragma unroll
    for (int pr = 0; pr < 2; ++pr) {
        const int imgA = img0 + pr * 2;
        const int imgB = imgA + 1;

        // ---- issue all 6 loads up front (MLP) ----
        float4 vA0 = make_float4(0.f,0.f,0.f,0.f), vA1 = vA0, vA2 = vA0;
        float4 vB0 = vA0, vB1 = vA0, vB2 = vA0;
        if (imgA < bsz) {
            const float* ipA = x + (size_t)imgA * 784;
            vA0 = *reinterpret_cast<const float4*>(ipA + 4 * lane);
            vA1 = *reinterpret_cast<const float4*>(ipA + 4 * j1);
            if (lane < 40) vA2 = *reinterpret_cast<const float4*>(ipA + 4 * j2);
        }
        if (imgB < bsz) {
            const float* ipB = x + (size_t)imgB * 784;
            vB0 = *reinterpret_cast<const float4*>(ipB + 4 * lane);
            vB1 = *reinterpret_cast<const float4*>(ipB + 4 * j1);
            if (lane < 40) vB2 = *reinterpret_cast<const float4*>(ipB + 4 * j2);
        }

        // ---- per-lane masked contributions ----
        float aA0 = 0.f, aA1 = 0.f, aA2 = 0.f, aA3 = 0.f;
        float aB0 = 0.f, aB1 = 0.f, aB2 = 0.f, aB3 = 0.f;
        {
            // slot r=0
            float h2 = vA0.x + vA0.y, h4 = h2 + vA0.z + vA0.w;
            float c  = (m0 == 0) ? h4 : ((m0 == 1) ? h2 : 0.f);
            aA0 += (p0 == 0) ? c : 0.f; aA1 += (p0 == 1) ? c : 0.f;
            aA2 += (p0 == 2) ? c : 0.f; aA3 += (p0 == 3) ? c : 0.f;
            h2 = vB0.x + vB0.y; h4 = h2 + vB0.z + vB0.w;
            c  = (m0 == 0) ? h4 : ((m0 == 1) ? h2 : 0.f);
            aB0 += (p0 == 0) ? c : 0.f; aB1 += (p0 == 1) ? c : 0.f;
            aB2 += (p0 == 2) ? c : 0.f; aB3 += (p0 == 3) ? c : 0.f;
            // slot r=1
            h2 = vA1.x + vA1.y; h4 = h2 + vA1.z + vA1.w;
            c  = (m1 == 0) ? h4 : ((m1 == 1) ? h2 : 0.f);
            aA0 += (p1 == 0) ? c : 0.f; aA1 += (p1 == 1) ? c : 0.f;
            aA2 += (p1 == 2) ? c : 0.f; aA3 += (p1 == 3) ? c : 0.f;
            h2 = vB1.x + vB1.y; h4 = h2 + vB1.z + vB1.w;
            c  = (m1 == 0) ? h4 : ((m1 == 1) ? h2 : 0.f);
            aB0 += (p1 == 0) ? c : 0.f; aB1 += (p1 == 1) ? c : 0.f;
            aB2 += (p1 == 2) ? c : 0.f; aB3 += (p1 == 3) ? c : 0.f;
            // slot r=2 (only lanes < 40 loaded; p2==4 for j>=168 anyway)
            h2 = vA2.x + vA2.y; h4 = h2 + vA2.z + vA2.w;
            c  = (m2 == 0) ? h4 : ((m2 == 1) ? h2 : 0.f);
            aA0 += (p2 == 0) ? c : 0.f; aA1 += (p2 == 1) ? c : 0.f;
            aA2 += (p2 == 2) ? c : 0.f; aA3 += (p2 == 3) ? c : 0.f;
            h2 = vB2.x + vB2.y; h4 = h2 + vB2.z + vB2.w;
            c  = (m2 == 0) ? h4 : ((m2 == 1) ? h2 : 0.f);
            aB0 += (p2 == 0) ? c : 0.f; aB1 += (p2 == 1) ? c : 0.f;
            aB2 += (p2 == 2) ? c : 0.f; aB3 += (p2 == 3) ? c : 0.f;
        }

        // ---- two independent butterflies (compiler interleaves) ----
        #pragma unroll
        for (int off = 1; off < 64; off <<= 1) {
            aA0 += __shfl_xor(aA0, off, 64);
            aB0 += __shfl_xor(aB0, off, 64);
            aA1 += __shfl_xor(aA1, off, 64);
            aB1 += __shfl_xor(aB1, off, 64);
            aA2 += __shfl_xor(aA2, off, 64);
            aB2 += __shfl_xor(aB2, off, 64);
            aA3 += __shfl_xor(aA3, off, 64);
            aB3 += __shfl_xor(aB3, off, 64);
        }

        const float k = 1.0f / 36.0f;
        const float cA0 = __cosf(aA0 * k), cA1 = __cosf(aA1 * k);
        const float cA2 = __cosf(aA2 * k), cA3 = __cosf(aA3 * k);
        const float cB0 = __cosf(aB0 * k), cB1 = __cosf(aB1 * k);
        const float cB2 = __cosf(aB2 * k), cB3 = __cosf(aB3 * k);

        const float zA1 = cA0 * cA1, zA2 = zA1 * cA2, zA3 = zA2 * cA3, zA0 = cA1 * cA2 * cA3;
        const float zB1 = cB0 * cB1, zB2 = zB1 * cB2, zB3 = zB2 * cB3, zB0 = cB1 * cB2 * cB3;

        if (imgA < bsz) {
            if (lane == 0) {
                float4 zz; zz.x = zA0; zz.y = zA1; zz.z = zA2; zz.w = zA3;
                *reinterpret_cast<float4*>(z_out + (size_t)imgA * 4) = zz;
            }
            s1[0] += zA0; s1[1] += zA1; s1[2] += zA2; s1[3] += zA3;
            s2[0] += zA0*zA0; s2[1] += zA1*zA1; s2[2] += zA2*zA2; s2[3] += zA3*zA3;
        }
        if (imgB < bsz) {
            if (lane == 0) {
                float4 zz; zz.x = zB0; zz.y = zB1; zz.z = zB2; zz.w = zB3;
                *reinterpret_cast<float4*>(z_out + (size_t)imgB * 4) = zz;
            }
            s1[0] += zB0; s1[1] += zB1; s1[2] += zB2; s1[3] += zB3;
            s2[0] += zB0*zB0; s2[1] += zB1*zB1; s2[2] += zB2*zB2; s2[3] += zB3*zB3;
        }
    }

    // combine 4 waves' (identical-per-lane) partials -> 8 floats per block
    __shared__ float ps[4][8];
    if (lane == 0) {
        #pragma unroll
        for (int k = 0; k < 4; ++k) { ps[w][k] = s1[k]; ps[w][4 + k] = s2[k]; }
    }
    __syncthreads();
    if (t < 8) {
        partials[blockIdx.x * 8 + t] = (ps[0][t] + ps[1][t]) + (ps[2][t] + ps[3][t]);
    }
}

// Every block redundantly reduces the partials table (L2/L3-resident, 128 KB),
// computes {mean, scale}, then normalizes its own 256 images. No serial phase.
__global__ __launch_bounds__(256) void qnat_k2(const float* __restrict__ z,
                                               const float* __restrict__ partials,
                                               const float* __restrict__ gamma,
                                               const float* __restrict__ beta,
                                               float* __restrict__ out,
                                               int NB, int bsz) {
    __shared__ float red[4][8];
    __shared__ float st[8];

    const int t = threadIdx.x, lane = t & 63, w = t >> 6;

    float acc[8] = {0.f,0.f,0.f,0.f,0.f,0.f,0.f,0.f};
    for (int r = t; r < NB; r += 256) {
        const float4 a = *reinterpret_cast<const float4*>(partials + r * 8);
        const float4 b = *reinterpret_cast<const float4*>(partials + r * 8 + 4);
        acc[0] += a.x; acc[1] += a.y; acc[2] += a.z; acc[3] += a.w;
        acc[4] += b.x; acc[5] += b.y; acc[6] += b.z; acc[7] += b.w;
    }
    #pragma unroll
    for (int off = 1; off < 64; off <<= 1) {
        #pragma unroll
        for (int k = 0; k < 8; ++k) acc[k] += __shfl_xor(acc[k], off, 64);
    }
    if (lane == 0) {
        #pragma unroll
        for (int k = 0; k < 8; ++k) red[w][k] = acc[k];
    }
    __syncthreads();
    if (t < 8) st[t] = (red[0][t] + red[1][t]) + (red[2][t] + red[3][t]);
    __syncthreads();
    if (t < 4) {
        const double invB = 1.0 / (double)bsz;
        const double m   = (double)st[t] * invB;
        const double var = (double)st[4 + t] * invB - m * m;
        st[t]     = (float)m;
        st[4 + t] = gamma[t] * rsqrtf((float)var + EPS);
    }
    __syncthreads();

    const int img = blockIdx.x * 256 + t;
    if (img < bsz) {
        const float4 zv = reinterpret_cast<const float4*>(z)[img];
        float4 o;
        o.x = (zv.x - st[0]) * st[4] + beta[0];
        o.y = (zv.y - st[1]) * st[5] + beta[1];
        o.z = (zv.z - st[2]) * st[6] + beta[2];
        o.w = (zv.w - st[3]) * st[7] + beta[3];
        reinterpret_cast<float4*>(out)[img] = o;
    }
}

extern "C" void kernel_launch(void* const* d_in, const int* in_sizes, int n_in,
                              void* d_out, int out_size, void* d_ws, size_t ws_size,
                              hipStream_t stream) {
    const float* x     = (const float*)d_in[0];
    const float* gamma = (const float*)d_in[1];
    const float* beta  = (const float*)d_in[2];
    float* out = (float*)d_out;

    const int bsz = in_sizes[0] / 784;
    const int NB  = (bsz + 15) / 16;

    float* z        = (float*)d_ws;
    float* partials = (float*)((char*)d_ws + (size_t)bsz * 16);

    qnat_k1<<<NB, 256, 0, stream>>>(x, z, partials, bsz);
    qnat_k2<<<(bsz + 255) / 256, 256, 0, stream>>>(z, partials, gamma, beta, out, NB, bsz);
}

// Round 7
// 39.403 us; speedup vs baseline: 4.1314x; 1.0119x over previous
//
#include <hip/hip_runtime.h>

#define EPS 1e-5f

// Math: theta_p = mean(x[b,0,6p:6p+6,0:6]); c_p = cos(theta_p);
// CNOT chain (0,1)(1,2)(2,3)(3,0) is a classical XOR map =>
// z0=c1*c2*c3, z1=c0*c1, z2=c0*c1*c2, z3=c0*c1*c2*c3; then batchnorm over B.
//
// Needed bytes per image all lie in [0, 2688) = float4 j in [0,168). Read densely
// (sequential request stream, full 128B lines), mask unneeded elements in registers.
//
// Reduction: packed-halving butterfly. Steps xor1/xor2 fold the 4 per-lane
// accumulators so lane l owns var (l&3); steps xor4..32 finish the 64-lane sum.
// 7 shfls/image + 3 broadcast shfls (vs 24 for the naive 4-var butterfly).
//
// ws layout:
//   [0, bsz*16)            float z[bsz][4]
//   [bsz*16, +NB*32)       float partials[NB][8] = {sum[4], sumsq[4]},  NB = ceil(bsz/16)

__global__ __launch_bounds__(256) void qnat_k1(const float* __restrict__ x,
                                               float* __restrict__ z_out,
                                               float* __restrict__ partials,
                                               int bsz) {
    const int t    = threadIdx.x;
    const int lane = t & 63;
    const int w    = t >> 6;                  // wave 0..3
    const int img0 = blockIdx.x * 16 + w * 4; // this wave's 4 consecutive images

    const bool b0 = (lane & 1) != 0;
    const bool b1 = (lane & 2) != 0;
    const int  k  = lane & 3;

    // per-lane slot constants (j = r*64 + lane)
    const int j1 = 64 + lane, j2 = 128 + lane;
    const int m0 = lane % 7, p0 = lane / 42;
    const int m1 = j1 % 7,   p1 = j1 / 42;
    const int m2 = j2 % 7,   p2 = j2 / 42;

    float s1 = 0.f, s2 = 0.f;   // per-lane scalar: accumulates z_{lane&3}

    #pragma unroll
    for (int pr = 0; pr < 2; ++pr) {
        const int imgA = img0 + pr * 2;
        const int imgB = imgA + 1;

        // ---- issue all 6 loads up front (MLP) ----
        float4 vA0 = make_float4(0.f,0.f,0.f,0.f), vA1 = vA0, vA2 = vA0;
        float4 vB0 = vA0, vB1 = vA0, vB2 = vA0;
        if (imgA < bsz) {
            const float* ipA = x + (size_t)imgA * 784;
            vA0 = *reinterpret_cast<const float4*>(ipA + 4 * lane);
            vA1 = *reinterpret_cast<const float4*>(ipA + 4 * j1);
            if (lane < 40) vA2 = *reinterpret_cast<const float4*>(ipA + 4 * j2);
        }
        if (imgB < bsz) {
            const float* ipB = x + (size_t)imgB * 784;
            vB0 = *reinterpret_cast<const float4*>(ipB + 4 * lane);
            vB1 = *reinterpret_cast<const float4*>(ipB + 4 * j1);
            if (lane < 40) vB2 = *reinterpret_cast<const float4*>(ipB + 4 * j2);
        }

        // ---- per-lane masked contributions ----
        float aA0 = 0.f, aA1 = 0.f, aA2 = 0.f, aA3 = 0.f;
        float aB0 = 0.f, aB1 = 0.f, aB2 = 0.f, aB3 = 0.f;
        {
            float h2 = vA0.x + vA0.y, h4 = h2 + vA0.z + vA0.w;
            float c  = (m0 == 0) ? h4 : ((m0 == 1) ? h2 : 0.f);
            aA0 += (p0 == 0) ? c : 0.f; aA1 += (p0 == 1) ? c : 0.f;
            aA2 += (p0 == 2) ? c : 0.f; aA3 += (p0 == 3) ? c : 0.f;
            h2 = vB0.x + vB0.y; h4 = h2 + vB0.z + vB0.w;
            c  = (m0 == 0) ? h4 : ((m0 == 1) ? h2 : 0.f);
            aB0 += (p0 == 0) ? c : 0.f; aB1 += (p0 == 1) ? c : 0.f;
            aB2 += (p0 == 2) ? c : 0.f; aB3 += (p0 == 3) ? c : 0.f;

            h2 = vA1.x + vA1.y; h4 = h2 + vA1.z + vA1.w;
            c  = (m1 == 0) ? h4 : ((m1 == 1) ? h2 : 0.f);
            aA0 += (p1 == 0) ? c : 0.f; aA1 += (p1 == 1) ? c : 0.f;
            aA2 += (p1 == 2) ? c : 0.f; aA3 += (p1 == 3) ? c : 0.f;
            h2 = vB1.x + vB1.y; h4 = h2 + vB1.z + vB1.w;
            c  = (m1 == 0) ? h4 : ((m1 == 1) ? h2 : 0.f);
            aB0 += (p1 == 0) ? c : 0.f; aB1 += (p1 == 1) ? c : 0.f;
            aB2 += (p1 == 2) ? c : 0.f; aB3 += (p1 == 3) ? c : 0.f;

            h2 = vA2.x + vA2.y; h4 = h2 + vA2.z + vA2.w;
            c  = (m2 == 0) ? h4 : ((m2 == 1) ? h2 : 0.f);
            aA0 += (p2 == 0) ? c : 0.f; aA1 += (p2 == 1) ? c : 0.f;
            aA2 += (p2 == 2) ? c : 0.f; aA3 += (p2 == 3) ? c : 0.f;
            h2 = vB2.x + vB2.y; h4 = h2 + vB2.z + vB2.w;
            c  = (m2 == 0) ? h4 : ((m2 == 1) ? h2 : 0.f);
            aB0 += (p2 == 0) ? c : 0.f; aB1 += (p2 == 1) ? c : 0.f;
            aB2 += (p2 == 2) ? c : 0.f; aB3 += (p2 == 3) ? c : 0.f;
        }

        // ---- packed-halving butterfly (A and B interleaved) ----
        // step xor1: fold {a0,a1} and {a2,a3}; lane keeps var bit0 / 2+bit0
        float rA = __shfl_xor(b0 ? aA0 : aA1, 1, 64);
        float rB = __shfl_xor(b0 ? aB0 : aB1, 1, 64);
        float uA = (b0 ? aA1 : aA0) + rA;
        float uB = (b0 ? aB1 : aB0) + rB;
        rA = __shfl_xor(b0 ? aA2 : aA3, 1, 64);
        rB = __shfl_xor(b0 ? aB2 : aB3, 1, 64);
        float vA = (b0 ? aA3 : aA2) + rA;
        float vB = (b0 ? aB3 : aB2) + rB;
        // step xor2: fold u/v; lane ends owning var (lane&3)
        rA = __shfl_xor(b1 ? uA : vA, 2, 64);
        rB = __shfl_xor(b1 ? uB : vB, 2, 64);
        float wA = (b1 ? vA : uA) + rA;
        float wB = (b1 ? vB : uB) + rB;
        // steps xor4..xor32: finish 64-lane sum
        #pragma unroll
        for (int off = 4; off < 64; off <<= 1) {
            wA += __shfl_xor(wA, off, 64);
            wB += __shfl_xor(wB, off, 64);
        }

        const float kk = 1.0f / 36.0f;
        const float cA = __cosf(wA * kk);          // lane holds c_{lane&3}
        const float cB = __cosf(wB * kk);
        // quad broadcast: cm1 = c_{k^1}, cm2 = c_{k^2}, cm3 = c_{k^3}
        const float cm1A = __shfl_xor(cA, 1, 64);
        const float cm1B = __shfl_xor(cB, 1, 64);
        const float cm2A = __shfl_xor(cA, 2, 64);
        const float cm2B = __shfl_xor(cB, 2, 64);
        const float cm3A = __shfl_xor(cm2A, 1, 64);
        const float cm3B = __shfl_xor(cm2B, 1, 64);

        // z_{k} from quad values:
        // k=0: c1c2c3 = cm1*cm2*cm3 ; k=1: c0c1 = c*cm1 ;
        // k=2: c0c1c2 = c*cm2*cm3   ; k=3: c0c1c2c3 = c*cm1*cm2*cm3
        const float t3A = cm2A * cm3A, fullA = cm1A * t3A;
        const float t3B = cm2B * cm3B, fullB = cm1B * t3B;
        const float zA = (k == 0) ? fullA : (k == 1) ? cA * cm1A
                       : (k == 2) ? cA * t3A : cA * fullA;
        const float zB = (k == 0) ? fullB : (k == 1) ? cB * cm1B
                       : (k == 2) ? cB * t3B : cB * fullB;

        // store z: lanes 0-3 -> imgA, lanes 4-7 -> imgB (two coalesced 16B segments)
        if (lane < 8) {
            const int  im = (lane < 4) ? imgA : imgB;
            const float zz = (lane < 4) ? zA : zB;
            if (im < bsz) z_out[(size_t)im * 4 + k] = zz;
        }
        // per-lane stat accumulation (var = lane&3)
        const float zAm = (imgA < bsz) ? zA : 0.f;
        const float zBm = (imgB < bsz) ? zB : 0.f;
        s1 += zAm + zBm;
        s2 += zAm * zAm + zBm * zBm;
    }

    // combine 4 waves -> 8 floats per block (lanes 0-3 hold vars 0-3)
    __shared__ float ps[4][8];
    if (lane < 4) { ps[w][lane] = s1; ps[w][4 + lane] = s2; }
    __syncthreads();
    if (t < 8) {
        partials[blockIdx.x * 8 + t] = (ps[0][t] + ps[1][t]) + (ps[2][t] + ps[3][t]);
    }
}

// Every block redundantly reduces the partials table (L2/L3-resident, 128 KB),
// computes {mean, scale}, then normalizes its own 1024 images. 64 blocks total
// => partials re-read is 8 MB.
__global__ __launch_bounds__(256) void qnat_k2(const float* __restrict__ z,
                                               const float* __restrict__ partials,
                                               const float* __restrict__ gamma,
                                               const float* __restrict__ beta,
                                               float* __restrict__ out,
                                               int NB, int bsz) {
    __shared__ float red[4][8];
    __shared__ float st[8];

    const int t = threadIdx.x, lane = t & 63, w = t >> 6;

    float acc[8] = {0.f,0.f,0.f,0.f,0.f,0.f,0.f,0.f};
    for (int r = t; r < NB; r += 256) {
        const float4 a = *reinterpret_cast<const float4*>(partials + r * 8);
        const float4 b = *reinterpret_cast<const float4*>(partials + r * 8 + 4);
        acc[0] += a.x; acc[1] += a.y; acc[2] += a.z; acc[3] += a.w;
        acc[4] += b.x; acc[5] += b.y; acc[6] += b.z; acc[7] += b.w;
    }
    #pragma unroll
    for (int off = 1; off < 64; off <<= 1) {
        #pragma unroll
        for (int kk = 0; kk < 8; ++kk) acc[kk] += __shfl_xor(acc[kk], off, 64);
    }
    if (lane == 0) {
        #pragma unroll
        for (int kk = 0; kk < 8; ++kk) red[w][kk] = acc[kk];
    }
    __syncthreads();
    if (t < 8) st[t] = (red[0][t] + red[1][t]) + (red[2][t] + red[3][t]);
    __syncthreads();
    if (t < 4) {
        const double invB = 1.0 / (double)bsz;
        const double m   = (double)st[t] * invB;
        const double var = (double)st[4 + t] * invB - m * m;
        st[t]     = (float)m;
        st[4 + t] = gamma[t] * rsqrtf((float)var + EPS);
    }
    __syncthreads();

    const int img0 = blockIdx.x * 1024 + t;
    #pragma unroll
    for (int i = 0; i < 4; ++i) {
        const int img = img0 + i * 256;
        if (img < bsz) {
            const float4 zv = reinterpret_cast<const float4*>(z)[img];
            float4 o;
            o.x = (zv.x - st[0]) * st[4] + beta[0];
            o.y = (zv.y - st[1]) * st[5] + beta[1];
            o.z = (zv.z - st[2]) * st[6] + beta[2];
            o.w = (zv.w - st[3]) * st[7] + beta[3];
            reinterpret_cast<float4*>(out)[img] = o;
        }
    }
}

extern "C" void kernel_launch(void* const* d_in, const int* in_sizes, int n_in,
                              void* d_out, int out_size, void* d_ws, size_t ws_size,
                              hipStream_t stream) {
    const float* x     = (const float*)d_in[0];
    const float* gamma = (const float*)d_in[1];
    const float* beta  = (const float*)d_in[2];
    float* out = (float*)d_out;

    const int bsz = in_sizes[0] / 784;
    const int NB  = (bsz + 15) / 16;
    const int NB2 = (bsz + 1023) / 1024;

    float* z        = (float*)d_ws;
    float* partials = (float*)((char*)d_ws + (size_t)bsz * 16);

    qnat_k1<<<NB, 256, 0, stream>>>(x, z, partials, bsz);
    qnat_k2<<<NB2, 256, 0, stream>>>(z, partials, gamma, beta, out, NB, bsz);
}